// Round 2
// baseline (208.165 us; speedup 1.0000x reference)
//
#include <hip/hip_runtime.h>

#define NN 1024
#define DD 128

typedef __attribute__((ext_vector_type(8))) __bf16 bf16x8;
typedef __attribute__((ext_vector_type(4))) float f32x4;

__device__ __forceinline__ float us2f(unsigned short b) { return __uint_as_float(((unsigned)b) << 16); }
__device__ __forceinline__ unsigned short f2bf(float f) {
    unsigned x = __float_as_uint(f);
    unsigned r = (x + 0x7fffu + ((x >> 16) & 1u)) >> 16;   // RNE
    return (unsigned short)r;
}

// ---------------- adj (f32) -> split bf16 hi/lo ----------------
__global__ __launch_bounds__(256) void k_prep(
    const float* __restrict__ adj, unsigned short* __restrict__ aH, unsigned short* __restrict__ aL)
{
    int idx = (blockIdx.x * 256 + threadIdx.x) * 4;
    float4 a = *(const float4*)(adj + idx);
    ushort4 hv, lv;
    hv.x = f2bf(a.x); lv.x = f2bf(a.x - us2f(hv.x));
    hv.y = f2bf(a.y); lv.y = f2bf(a.y - us2f(hv.y));
    hv.z = f2bf(a.z); lv.z = f2bf(a.z - us2f(hv.z));
    hv.w = f2bf(a.w); lv.w = f2bf(a.w - us2f(hv.w));
    *(ushort4*)(aH + idx) = hv;
    *(ushort4*)(aL + idx) = lv;
}

// ---------------- node embedding: h = nf @ We + be ----------------
__global__ __launch_bounds__(256) void k_embed(
    const float* __restrict__ nf, const float* __restrict__ We,
    const float* __restrict__ be, float* __restrict__ h)
{
    int tid = threadIdx.x;
    int m = blockIdx.x * 2 + (tid >> 7);
    int d = tid & 127;
    float a = be[d];
#pragma unroll
    for (int k = 0; k < 3; ++k) a = fmaf(nf[m * 3 + k], We[k * DD + d], a);
    h[m * DD + d] = a;
}

// ---------------- u = h@Wu+bu (f32); v = h@Wv+bv stored transposed, split bf16 ----------------
__global__ __launch_bounds__(256) void k_uv(
    const float* __restrict__ h,
    const float* __restrict__ Wu, const float* __restrict__ bu,
    const float* __restrict__ Wv, const float* __restrict__ bv,
    float* __restrict__ u, unsigned short* __restrict__ vTh, unsigned short* __restrict__ vTl)
{
    int tid = threadIdx.x;
    int d = tid & 127, half = tid >> 7;
    int m0 = blockIdx.x * 4;
    const float* W = half ? Wv : Wu;
    const float* A = h + m0 * DD;            // wave-uniform addresses -> scalar loads
    float acc[4] = {0.f, 0.f, 0.f, 0.f};
#pragma unroll 8
    for (int k = 0; k < DD; ++k) {
        float w = W[k * DD + d];
#pragma unroll
        for (int r = 0; r < 4; ++r) acc[r] = fmaf(A[r * DD + k], w, acc[r]);
    }
    if (half == 0) {
        float bb = bu[d];
#pragma unroll
        for (int r = 0; r < 4; ++r) u[(m0 + r) * DD + d] = acc[r] + bb;
    } else {
        float bb = bv[d];
        ushort4 hv, lv;
        float v0 = acc[0] + bb, v1 = acc[1] + bb, v2 = acc[2] + bb, v3 = acc[3] + bb;
        hv.x = f2bf(v0); lv.x = f2bf(v0 - us2f(hv.x));
        hv.y = f2bf(v1); lv.y = f2bf(v1 - us2f(hv.y));
        hv.z = f2bf(v2); lv.z = f2bf(v2 - us2f(hv.z));
        hv.w = f2bf(v3); lv.w = f2bf(v3 - us2f(hv.w));
        *(ushort4*)(vTh + d * NN + m0) = hv;
        *(ushort4*)(vTl + d * NN + m0) = lv;
    }
}

// ---------------- agg = adj @ v via MFMA 16x16x32 bf16, split-precision A and B ----------------
__global__ __launch_bounds__(64) void k_agg(
    const unsigned short* __restrict__ adjH, const unsigned short* __restrict__ adjL,
    const unsigned short* __restrict__ vTh, const unsigned short* __restrict__ vTl,
    float* __restrict__ agg)
{
    int lane = threadIdx.x;
    int b = blockIdx.x;
    // XCD-preserving swizzle: the 8 blocks sharing an adj strip land on one XCD
    int nt = (b >> 3) & 7;
    int mt = (b & 7) | ((b >> 6) << 3);
    int m = lane & 15, quad = lane >> 4;
    const unsigned short* ah = adjH + (size_t)(mt * 16 + m) * NN + quad * 8;
    const unsigned short* al = adjL + (size_t)(mt * 16 + m) * NN + quad * 8;
    const unsigned short* bh = vTh + (size_t)(nt * 16 + m) * NN + quad * 8;
    const unsigned short* bl = vTl + (size_t)(nt * 16 + m) * NN + quad * 8;
    f32x4 acc = {0.f, 0.f, 0.f, 0.f};
#pragma unroll 4
    for (int kt = 0; kt < 32; ++kt) {
        bf16x8 aH = *(const bf16x8*)(ah + kt * 32);
        bf16x8 aL = *(const bf16x8*)(al + kt * 32);
        bf16x8 bH = *(const bf16x8*)(bh + kt * 32);
        bf16x8 bL = *(const bf16x8*)(bl + kt * 32);
        acc = __builtin_amdgcn_mfma_f32_16x16x32_bf16(aH, bH, acc, 0, 0, 0);
        acc = __builtin_amdgcn_mfma_f32_16x16x32_bf16(aH, bL, acc, 0, 0, 0);
        acc = __builtin_amdgcn_mfma_f32_16x16x32_bf16(aL, bH, acc, 0, 0, 0);
    }
    int row0 = mt * 16 + quad * 4;
    int col = nt * 16 + m;
#pragma unroll
    for (int r = 0; r < 4; ++r) agg[(row0 + r) * DD + col] = acc[r];
}

// ---------------- gate = sigmoid(u@WgA + agg@WgB + bg); h = relu(h + gate*agg) ----------------
__global__ __launch_bounds__(256) void k_gate(
    const float* __restrict__ u, const float* __restrict__ agg,
    const float* __restrict__ Wg, const float* __restrict__ bg,
    float* __restrict__ h)
{
    int tid = threadIdx.x;
    int d = tid & 127, rh = tid >> 7;
    int m0 = blockIdx.x * 4 + rh * 2;
    const float* WA = Wg;
    const float* WB = Wg + DD * DD;
    const float* Au = u + m0 * DD;
    const float* Ag = agg + m0 * DD;
    float acc[2] = {0.f, 0.f};
#pragma unroll 8
    for (int k = 0; k < DD; ++k) {
        float wa = WA[k * DD + d];
        float wb = WB[k * DD + d];
#pragma unroll
        for (int r = 0; r < 2; ++r)
            acc[r] = fmaf(Au[r * DD + k], wa, fmaf(Ag[r * DD + k], wb, acc[r]));
    }
    float bgd = bg[d];
#pragma unroll
    for (int r = 0; r < 2; ++r) {
        float z = acc[r] + bgd;
        float g = 1.f / (1.f + __expf(-z));
        float av = agg[(m0 + r) * DD + d];
        float hv = h[(m0 + r) * DD + d];
        float nh = fmaf(g, av, hv);
        h[(m0 + r) * DD + d] = nh > 0.f ? nh : 0.f;
    }
}

// ---------------- hi = h@Wc1[:D]+bc1, hj = h@Wc1[D:]; S1=sum(w*hi), S2=sum(w*hj) ----------------
__global__ __launch_bounds__(256) void k_cls(
    const float* __restrict__ h,
    const float* __restrict__ Wc1, const float* __restrict__ bc1,
    const float* __restrict__ Wc2,
    float* __restrict__ hi, float* __restrict__ hj,
    float* __restrict__ S1, float* __restrict__ S2)
{
    __shared__ float sred[2][4];
    int tid = threadIdx.x;
    int hh = tid & 127, half = tid >> 7;
    int m0 = blockIdx.x * 4;
    if (tid < 8) sred[tid >> 2][tid & 3] = 0.f;
    __syncthreads();
    const float* W = Wc1 + (half ? DD * DD : 0);
    const float* A = h + m0 * DD;
    float acc[4] = {0.f, 0.f, 0.f, 0.f};
#pragma unroll 8
    for (int k = 0; k < DD; ++k) {
        float w = W[k * DD + hh];
#pragma unroll
        for (int r = 0; r < 4; ++r) acc[r] = fmaf(A[r * DD + k], w, acc[r]);
    }
    float wv = Wc2[hh];
    float bcv = half ? 0.f : bc1[hh];
    float* out = half ? hj : hi;
#pragma unroll
    for (int r = 0; r < 4; ++r) {
        float val = acc[r] + bcv;
        out[(m0 + r) * DD + hh] = val;
        float p = val * wv;
#pragma unroll
        for (int off = 32; off; off >>= 1) p += __shfl_down(p, off);
        if ((tid & 63) == 0) atomicAdd(&sred[half][r], p);
    }
    __syncthreads();
    if (tid < 4) S1[m0 + tid] = sred[0][tid];
    else if (tid < 8) S2[m0 + tid - 4] = sred[1][tid - 4];
}

// ---------------- logits + loss; relu(x) = (x+|x|)/2 trick ----------------
__global__ __launch_bounds__(256) void k_edge(
    const float* __restrict__ hi, const float* __restrict__ hj,
    const float* __restrict__ S1, const float* __restrict__ S2,
    const float* __restrict__ Wc2, const float* __restrict__ bc2,
    const float* __restrict__ adj, const float* __restrict__ ew,
    float* __restrict__ outL, float* __restrict__ lossAcc)
{
    __shared__ float hiT[128][68];   // transposed; stride 68 keeps float4 rows 16B-aligned
    __shared__ float hjT[128][68];
    __shared__ float wS[128];
    __shared__ float lred;
    int tid = threadIdx.x;
    int i0 = (blockIdx.x >> 4) * 64, j0 = (blockIdx.x & 15) * 64;
    if (tid == 0) lred = 0.f;
    if (tid < 128) wS[tid] = Wc2[tid];
    for (int e = tid; e < 64 * 128; e += 256) {
        int r = e >> 7, hh = e & 127;
        hiT[hh][r] = hi[(i0 + r) * DD + hh];
        hjT[hh][r] = hj[(j0 + r) * DD + hh];
    }
    __syncthreads();
    int tx = tid & 15, ty = tid >> 4;
    float acc[4][4] = {};
#pragma unroll 4
    for (int hh = 0; hh < 128; ++hh) {
        f32x4 a = *(const f32x4*)&hiT[hh][ty * 4];
        f32x4 b = *(const f32x4*)&hjT[hh][tx * 4];
        float w = wS[hh];
#pragma unroll
        for (int p = 0; p < 4; ++p)
#pragma unroll
            for (int q = 0; q < 4; ++q) {
                float x = a[p] + b[q];
                acc[p][q] = fmaf(fabsf(x), w, acc[p][q]);   // |x| is a free modifier
            }
    }
    float bcv = bc2[0];
    float ls = 0.f;
#pragma unroll
    for (int p = 0; p < 4; ++p) {
        int i = i0 + ty * 4 + p;
        float s1 = S1[i];
        int jb = j0 + tx * 4;
        f32x4 s2 = *(const f32x4*)(S2 + jb);
        f32x4 lg;
#pragma unroll
        for (int q = 0; q < 4; ++q)
            lg[q] = fmaf(0.5f, acc[p][q] + s1 + s2[q], bcv);
        *(f32x4*)(outL + (size_t)i * NN + jb) = lg;
        f32x4 a4 = *(const f32x4*)(adj + (size_t)i * NN + jb);
        f32x4 e4 = *(const f32x4*)(ew + (size_t)i * NN + jb);
#pragma unroll
        for (int q = 0; q < 4; ++q) {
            float t = fmaf(lg[q], a4[q], -e4[q]);
            ls = fmaf(t, t, ls);
        }
    }
#pragma unroll
    for (int off = 32; off; off >>= 1) ls += __shfl_down(ls, off);
    if ((tid & 63) == 0) atomicAdd(&lred, ls);
    __syncthreads();
    if (tid == 0) atomicAdd(lossAcc, lred);
}

__global__ void k_loss(const float* __restrict__ lossAcc, float* __restrict__ outL)
{
    if (threadIdx.x == 0 && blockIdx.x == 0)
        outL[(size_t)NN * NN] = lossAcc[0] * (1.f / (1024.f * 1024.f));
}

extern "C" void kernel_launch(void* const* d_in, const int* in_sizes, int n_in,
                              void* d_out, int out_size, void* d_ws, size_t ws_size,
                              hipStream_t stream)
{
    const float* nf  = (const float*)d_in[0];
    const float* adj = (const float*)d_in[1];
    const float* ew  = (const float*)d_in[2];
    const float* We  = (const float*)d_in[3];
    const float* be  = (const float*)d_in[4];
    const float* Wu  = (const float*)d_in[5];
    const float* bu  = (const float*)d_in[6];
    const float* Wv  = (const float*)d_in[7];
    const float* bv  = (const float*)d_in[8];
    const float* Wg  = (const float*)d_in[9];
    const float* bg  = (const float*)d_in[10];
    const float* Wc1 = (const float*)d_in[11];
    const float* bc1 = (const float*)d_in[12];
    const float* Wc2 = (const float*)d_in[13];
    const float* bc2 = (const float*)d_in[14];

    float* ws = (float*)d_ws;
    float* h   = ws;                                         // 131072 f32
    float* u   = ws + 131072;                                // 131072 f32 (reused as hi)
    unsigned short* vTh = (unsigned short*)(ws + 262144);    // 131072 bf16
    unsigned short* vTl = (unsigned short*)(ws + 327680);    // 131072 bf16
    float* agg = ws + 393216;                                // 131072 f32 (reused as hj)
    unsigned short* adjH = (unsigned short*)(ws + 524288);   // 1M bf16
    unsigned short* adjL = (unsigned short*)(ws + 1048576);  // 1M bf16
    float* S1  = ws + 1572864;                               // 1024
    float* S2  = ws + 1573888;                               // 1024
    float* lossAcc = ws + 1574912;                           // 1
    float* hi = u;
    float* hj = agg;

    hipMemsetAsync(lossAcc, 0, sizeof(float), stream);
    k_prep<<<1024, 256, 0, stream>>>(adj, adjH, adjL);
    k_embed<<<512, 256, 0, stream>>>(nf, We, be, h);
    for (int l = 0; l < 3; ++l) {
        k_uv<<<256, 256, 0, stream>>>(h, Wu + l * 16384, bu + l * 128,
                                      Wv + l * 16384, bv + l * 128, u, vTh, vTl);
        k_agg<<<512, 64, 0, stream>>>(adjH, adjL, vTh, vTl, agg);
        k_gate<<<256, 256, 0, stream>>>(u, agg, Wg + l * 32768, bg + l * 128, h);
    }
    k_cls<<<256, 256, 0, stream>>>(h, Wc1, bc1, Wc2, hi, hj, S1, S2);
    k_edge<<<256, 256, 0, stream>>>(hi, hj, S1, S2, Wc2, bc2, adj, ew,
                                    (float*)d_out, lossAcc);
    k_loss<<<1, 64, 0, stream>>>(lossAcc, (float*)d_out);
}

// Round 3
// 187.223 us; speedup vs baseline: 1.1119x; 1.1119x over previous
//
#include <hip/hip_runtime.h>

#define NN 1024
#define DD 128

typedef __attribute__((ext_vector_type(8))) __bf16 bf16x8;
typedef __attribute__((ext_vector_type(4))) float f32x4;

__device__ __forceinline__ float us2f(unsigned short b) { return __uint_as_float(((unsigned)b) << 16); }
__device__ __forceinline__ unsigned short f2bf(float f) {
    unsigned x = __float_as_uint(f);
    return (unsigned short)((x + 0x7fffu + ((x >> 16) & 1u)) >> 16);   // RNE
}

// ---- fused: adj->split bf16 (blocks 0..1023) | embed + u/v GEMM layer0 (blocks 1024..1279) ----
__global__ __launch_bounds__(256) void k_prep_embuv(
    const float* __restrict__ adj, unsigned short* __restrict__ aH, unsigned short* __restrict__ aL,
    const float* __restrict__ nf, const float* __restrict__ We, const float* __restrict__ be,
    const float* __restrict__ Wu, const float* __restrict__ bu,
    const float* __restrict__ Wv, const float* __restrict__ bv,
    float* __restrict__ h, float* __restrict__ u,
    unsigned short* __restrict__ vTh, unsigned short* __restrict__ vTl,
    float* __restrict__ lossAcc, unsigned* __restrict__ counter)
{
    __shared__ float hS[4][DD];
    int b = blockIdx.x, tid = threadIdx.x;
    if (b < 1024) {
        int idx = (b * 256 + tid) * 4;
        float4 a = *(const float4*)(adj + idx);
        ushort4 hv, lv;
        hv.x = f2bf(a.x); lv.x = f2bf(a.x - us2f(hv.x));
        hv.y = f2bf(a.y); lv.y = f2bf(a.y - us2f(hv.y));
        hv.z = f2bf(a.z); lv.z = f2bf(a.z - us2f(hv.z));
        hv.w = f2bf(a.w); lv.w = f2bf(a.w - us2f(hv.w));
        *(ushort4*)(aH + idx) = hv;
        *(ushort4*)(aL + idx) = lv;
        if (b == 0 && tid == 0) { *lossAcc = 0.f; *counter = 0u; }
        return;
    }
    int m0 = (b - 1024) * 4;
    int d = tid & 127, half = tid >> 7;
    float hr[4];
#pragma unroll
    for (int r = 0; r < 4; ++r) {
        float a = be[d];
#pragma unroll
        for (int k = 0; k < 3; ++k) a = fmaf(nf[(m0 + r) * 3 + k], We[k * DD + d], a);
        hr[r] = a;
    }
    if (half == 0) {
#pragma unroll
        for (int r = 0; r < 4; ++r) { h[(m0 + r) * DD + d] = hr[r]; hS[r][d] = hr[r]; }
    }
    __syncthreads();
    const float* W = half ? Wv : Wu;
    float acc[4] = {0.f, 0.f, 0.f, 0.f};
#pragma unroll 4
    for (int k4 = 0; k4 < DD; k4 += 4) {
        f32x4 h0 = *(const f32x4*)&hS[0][k4];
        f32x4 h1 = *(const f32x4*)&hS[1][k4];
        f32x4 h2 = *(const f32x4*)&hS[2][k4];
        f32x4 h3 = *(const f32x4*)&hS[3][k4];
#pragma unroll
        for (int kk = 0; kk < 4; ++kk) {
            float w = W[(k4 + kk) * DD + d];
            acc[0] = fmaf(h0[kk], w, acc[0]);
            acc[1] = fmaf(h1[kk], w, acc[1]);
            acc[2] = fmaf(h2[kk], w, acc[2]);
            acc[3] = fmaf(h3[kk], w, acc[3]);
        }
    }
    if (half == 0) {
        float bb = bu[d];
#pragma unroll
        for (int r = 0; r < 4; ++r) u[(m0 + r) * DD + d] = acc[r] + bb;
    } else {
        float bb = bv[d];
        float v0 = acc[0] + bb, v1 = acc[1] + bb, v2 = acc[2] + bb, v3 = acc[3] + bb;
        ushort4 hv, lv;
        hv.x = f2bf(v0); lv.x = f2bf(v0 - us2f(hv.x));
        hv.y = f2bf(v1); lv.y = f2bf(v1 - us2f(hv.y));
        hv.z = f2bf(v2); lv.z = f2bf(v2 - us2f(hv.z));
        hv.w = f2bf(v3); lv.w = f2bf(v3 - us2f(hv.w));
        *(ushort4*)(vTh + d * NN + m0) = hv;
        *(ushort4*)(vTl + d * NN + m0) = lv;
    }
}

// ---- agg partials: P[kc] = adj[:, kc-chunk] @ v[kc-chunk, :], MFMA split-precision ----
__global__ __launch_bounds__(256) void k_agg(
    const unsigned short* __restrict__ adjH, const unsigned short* __restrict__ adjL,
    const unsigned short* __restrict__ vTh, const unsigned short* __restrict__ vTl,
    float* __restrict__ P)
{
    int tid = threadIdx.x, lane = tid & 63, w = tid >> 6;
    int b = blockIdx.x;
    int nt = b >> 7;                 // 0..7
    int mt = (b >> 1) & 63;          // 0..63
    int kc = ((b & 1) << 2) | w;     // 0..7
    int m = lane & 15, quad = lane >> 4;
    int k0 = kc * 128 + quad * 8;
    const unsigned short* ah = adjH + (size_t)(mt * 16 + m) * NN + k0;
    const unsigned short* al = adjL + (size_t)(mt * 16 + m) * NN + k0;
    const unsigned short* bh = vTh + (size_t)(nt * 16 + m) * NN + k0;
    const unsigned short* bl = vTl + (size_t)(nt * 16 + m) * NN + k0;
    f32x4 acc = {0.f, 0.f, 0.f, 0.f};
#pragma unroll
    for (int kt = 0; kt < 4; ++kt) {
        bf16x8 aH = *(const bf16x8*)(ah + kt * 32);
        bf16x8 aL = *(const bf16x8*)(al + kt * 32);
        bf16x8 bH = *(const bf16x8*)(bh + kt * 32);
        bf16x8 bL = *(const bf16x8*)(bl + kt * 32);
        acc = __builtin_amdgcn_mfma_f32_16x16x32_bf16(aH, bH, acc, 0, 0, 0);
        acc = __builtin_amdgcn_mfma_f32_16x16x32_bf16(aH, bL, acc, 0, 0, 0);
        acc = __builtin_amdgcn_mfma_f32_16x16x32_bf16(aL, bH, acc, 0, 0, 0);
    }
    float* Pk = P + (size_t)kc * (NN * DD);
    int row0 = mt * 16 + quad * 4;
    int col = nt * 16 + m;
#pragma unroll
    for (int r = 0; r < 4; ++r) Pk[(row0 + r) * DD + col] = acc[r];
}

// ---- fused: sum partials + gate + h-update + next-layer u/v GEMM ----
__global__ __launch_bounds__(256) void k_gateuv(
    const float* __restrict__ P, float* __restrict__ u, float* __restrict__ h,
    const float* __restrict__ Wg, const float* __restrict__ bg,
    const float* __restrict__ Wun, const float* __restrict__ bun,
    const float* __restrict__ Wvn, const float* __restrict__ bvn,
    unsigned short* __restrict__ vTh, unsigned short* __restrict__ vTl)
{
    __shared__ float uS[4][DD], aS[4][DD], hS[4][DD];
    int tid = threadIdx.x;
    int m0 = blockIdx.x * 4;
    int d = tid & 127, half = tid >> 7;
#pragma unroll
    for (int e = tid; e < 512; e += 256) {
        int r = e >> 7, dd = e & 127;
        int idx = (m0 + r) * DD + dd;
        float s = 0.f;
#pragma unroll
        for (int c = 0; c < 8; ++c) s += P[(size_t)c * (NN * DD) + idx];
        aS[r][dd] = s;
        uS[r][dd] = u[idx];
    }
    __syncthreads();
    const float* WA = Wg;
    const float* WB = Wg + DD * DD;
    int r0 = half * 2;
    float acc[2] = {0.f, 0.f};
#pragma unroll 4
    for (int k4 = 0; k4 < DD; k4 += 4) {
        f32x4 u0 = *(const f32x4*)&uS[r0][k4];
        f32x4 u1 = *(const f32x4*)&uS[r0 + 1][k4];
        f32x4 a0 = *(const f32x4*)&aS[r0][k4];
        f32x4 a1 = *(const f32x4*)&aS[r0 + 1][k4];
#pragma unroll
        for (int kk = 0; kk < 4; ++kk) {
            float wa = WA[(k4 + kk) * DD + d];
            float wb = WB[(k4 + kk) * DD + d];
            acc[0] = fmaf(u0[kk], wa, fmaf(a0[kk], wb, acc[0]));
            acc[1] = fmaf(u1[kk], wa, fmaf(a1[kk], wb, acc[1]));
        }
    }
    float bgd = bg[d];
#pragma unroll
    for (int rr = 0; rr < 2; ++rr) {
        int r = r0 + rr;
        float g = 1.f / (1.f + __expf(-(acc[rr] + bgd)));
        float nh = fmaf(g, aS[r][d], h[(m0 + r) * DD + d]);
        nh = nh > 0.f ? nh : 0.f;
        h[(m0 + r) * DD + d] = nh;
        hS[r][d] = nh;
    }
    __syncthreads();
    const float* W = half ? Wvn : Wun;
    float av[4] = {0.f, 0.f, 0.f, 0.f};
#pragma unroll 4
    for (int k4 = 0; k4 < DD; k4 += 4) {
        f32x4 h0 = *(const f32x4*)&hS[0][k4];
        f32x4 h1 = *(const f32x4*)&hS[1][k4];
        f32x4 h2 = *(const f32x4*)&hS[2][k4];
        f32x4 h3 = *(const f32x4*)&hS[3][k4];
#pragma unroll
        for (int kk = 0; kk < 4; ++kk) {
            float w = W[(k4 + kk) * DD + d];
            av[0] = fmaf(h0[kk], w, av[0]);
            av[1] = fmaf(h1[kk], w, av[1]);
            av[2] = fmaf(h2[kk], w, av[2]);
            av[3] = fmaf(h3[kk], w, av[3]);
        }
    }
    if (half == 0) {
        float bb = bun[d];
#pragma unroll
        for (int r = 0; r < 4; ++r) u[(m0 + r) * DD + d] = av[r] + bb;
    } else {
        float bb = bvn[d];
        float v0 = av[0] + bb, v1 = av[1] + bb, v2 = av[2] + bb, v3 = av[3] + bb;
        ushort4 hv, lv;
        hv.x = f2bf(v0); lv.x = f2bf(v0 - us2f(hv.x));
        hv.y = f2bf(v1); lv.y = f2bf(v1 - us2f(hv.y));
        hv.z = f2bf(v2); lv.z = f2bf(v2 - us2f(hv.z));
        hv.w = f2bf(v3); lv.w = f2bf(v3 - us2f(hv.w));
        *(ushort4*)(vTh + d * NN + m0) = hv;
        *(ushort4*)(vTl + d * NN + m0) = lv;
    }
}

// ---- fused: sum partials + gate(2) + h-update + classifier GEMMs + S1/S2 ----
__global__ __launch_bounds__(256) void k_gatecls(
    const float* __restrict__ P, float* __restrict__ u, float* __restrict__ h,
    const float* __restrict__ Wg, const float* __restrict__ bg,
    const float* __restrict__ Wc1, const float* __restrict__ bc1, const float* __restrict__ Wc2,
    float* __restrict__ hi, float* __restrict__ hj,
    float* __restrict__ S1, float* __restrict__ S2)
{
    __shared__ float uS[4][DD], aS[4][DD], hS[4][DD];
    __shared__ float sred[2][4];
    int tid = threadIdx.x;
    int m0 = blockIdx.x * 4;
    int d = tid & 127, half = tid >> 7;
    if (tid < 8) sred[tid >> 2][tid & 3] = 0.f;
#pragma unroll
    for (int e = tid; e < 512; e += 256) {
        int r = e >> 7, dd = e & 127;
        int idx = (m0 + r) * DD + dd;
        float s = 0.f;
#pragma unroll
        for (int c = 0; c < 8; ++c) s += P[(size_t)c * (NN * DD) + idx];
        aS[r][dd] = s;
        uS[r][dd] = u[idx];
    }
    __syncthreads();
    const float* WA = Wg;
    const float* WB = Wg + DD * DD;
    int r0 = half * 2;
    float acc[2] = {0.f, 0.f};
#pragma unroll 4
    for (int k4 = 0; k4 < DD; k4 += 4) {
        f32x4 u0 = *(const f32x4*)&uS[r0][k4];
        f32x4 u1 = *(const f32x4*)&uS[r0 + 1][k4];
        f32x4 a0 = *(const f32x4*)&aS[r0][k4];
        f32x4 a1 = *(const f32x4*)&aS[r0 + 1][k4];
#pragma unroll
        for (int kk = 0; kk < 4; ++kk) {
            float wa = WA[(k4 + kk) * DD + d];
            float wb = WB[(k4 + kk) * DD + d];
            acc[0] = fmaf(u0[kk], wa, fmaf(a0[kk], wb, acc[0]));
            acc[1] = fmaf(u1[kk], wa, fmaf(a1[kk], wb, acc[1]));
        }
    }
    float bgd = bg[d];
#pragma unroll
    for (int rr = 0; rr < 2; ++rr) {
        int r = r0 + rr;
        float g = 1.f / (1.f + __expf(-(acc[rr] + bgd)));
        float nh = fmaf(g, aS[r][d], h[(m0 + r) * DD + d]);
        nh = nh > 0.f ? nh : 0.f;
        hS[r][d] = nh;
    }
    __syncthreads();
    const float* W = Wc1 + (half ? DD * DD : 0);
    float av[4] = {0.f, 0.f, 0.f, 0.f};
#pragma unroll 4
    for (int k4 = 0; k4 < DD; k4 += 4) {
        f32x4 h0 = *(const f32x4*)&hS[0][k4];
        f32x4 h1 = *(const f32x4*)&hS[1][k4];
        f32x4 h2 = *(const f32x4*)&hS[2][k4];
        f32x4 h3 = *(const f32x4*)&hS[3][k4];
#pragma unroll
        for (int kk = 0; kk < 4; ++kk) {
            float w = W[(k4 + kk) * DD + d];
            av[0] = fmaf(h0[kk], w, av[0]);
            av[1] = fmaf(h1[kk], w, av[1]);
            av[2] = fmaf(h2[kk], w, av[2]);
            av[3] = fmaf(h3[kk], w, av[3]);
        }
    }
    float wv = Wc2[d];
    float bcv = half ? 0.f : bc1[d];
    float* out = half ? hj : hi;
    int lane = tid & 63;
#pragma unroll
    for (int r = 0; r < 4; ++r) {
        float val = av[r] + bcv;
        out[(m0 + r) * DD + d] = val;
        float p = val * wv;
#pragma unroll
        for (int off = 32; off; off >>= 1) p += __shfl_down(p, off);
        if (lane == 0) atomicAdd(&sred[half][r], p);
    }
    __syncthreads();
    if (tid < 4) S1[m0 + tid] = sred[0][tid];
    else if (tid < 8) S2[m0 + tid - 4] = sred[1][tid - 4];
}

// ---- logits + loss; relu(x) = (x+|x|)/2 trick; last block finalizes loss ----
__global__ __launch_bounds__(256) void k_edge(
    const float* __restrict__ hi, const float* __restrict__ hj,
    const float* __restrict__ S1, const float* __restrict__ S2,
    const float* __restrict__ Wc2, const float* __restrict__ bc2,
    const float* __restrict__ adj, const float* __restrict__ ew,
    float* __restrict__ outL, float* __restrict__ lossAcc, unsigned* __restrict__ counter)
{
    __shared__ float hiT[128][68];   // stride 68 keeps float4 rows 16B-aligned
    __shared__ float hjT[128][68];
    __shared__ float wS[128];
    __shared__ float lred;
    int tid = threadIdx.x;
    int i0 = (blockIdx.x >> 4) * 64, j0 = (blockIdx.x & 15) * 64;
    if (tid == 0) lred = 0.f;
    if (tid < 128) wS[tid] = Wc2[tid];
    for (int e = tid; e < 64 * 128; e += 256) {
        int r = e >> 7, hh = e & 127;
        hiT[hh][r] = hi[(i0 + r) * DD + hh];
        hjT[hh][r] = hj[(j0 + r) * DD + hh];
    }
    __syncthreads();
    int tx = tid & 15, ty = tid >> 4;
    float acc[4][4] = {};
#pragma unroll 4
    for (int hh = 0; hh < 128; ++hh) {
        f32x4 a = *(const f32x4*)&hiT[hh][ty * 4];
        f32x4 b = *(const f32x4*)&hjT[hh][tx * 4];
        float w = wS[hh];
#pragma unroll
        for (int p = 0; p < 4; ++p)
#pragma unroll
            for (int q = 0; q < 4; ++q) {
                float x = a[p] + b[q];
                acc[p][q] = fmaf(fabsf(x), w, acc[p][q]);
            }
    }
    float bcv = bc2[0];
    float ls = 0.f;
#pragma unroll
    for (int p = 0; p < 4; ++p) {
        int i = i0 + ty * 4 + p;
        float s1 = S1[i];
        int jb = j0 + tx * 4;
        f32x4 s2 = *(const f32x4*)(S2 + jb);
        f32x4 lg;
#pragma unroll
        for (int q = 0; q < 4; ++q)
            lg[q] = fmaf(0.5f, acc[p][q] + s1 + s2[q], bcv);
        *(f32x4*)(outL + (size_t)i * NN + jb) = lg;
        f32x4 a4 = *(const f32x4*)(adj + (size_t)i * NN + jb);
        f32x4 e4 = *(const f32x4*)(ew + (size_t)i * NN + jb);
#pragma unroll
        for (int q = 0; q < 4; ++q) {
            float t = fmaf(lg[q], a4[q], -e4[q]);
            ls = fmaf(t, t, ls);
        }
    }
#pragma unroll
    for (int off = 32; off; off >>= 1) ls += __shfl_down(ls, off);
    if ((tid & 63) == 0) atomicAdd(&lred, ls);
    __syncthreads();
    if (tid == 0) {
        atomicAdd(lossAcc, lred);
        __threadfence();
        unsigned old = atomicAdd(counter, 1u);
        if (old == 255u) {
            __threadfence();
            outL[(size_t)NN * NN] = (*(volatile float*)lossAcc) * (1.f / (1024.f * 1024.f));
        }
    }
}

extern "C" void kernel_launch(void* const* d_in, const int* in_sizes, int n_in,
                              void* d_out, int out_size, void* d_ws, size_t ws_size,
                              hipStream_t stream)
{
    const float* nf  = (const float*)d_in[0];
    const float* adj = (const float*)d_in[1];
    const float* ew  = (const float*)d_in[2];
    const float* We  = (const float*)d_in[3];
    const float* be  = (const float*)d_in[4];
    const float* Wu  = (const float*)d_in[5];
    const float* bu  = (const float*)d_in[6];
    const float* Wv  = (const float*)d_in[7];
    const float* bv  = (const float*)d_in[8];
    const float* Wg  = (const float*)d_in[9];
    const float* bg  = (const float*)d_in[10];
    const float* Wc1 = (const float*)d_in[11];
    const float* bc1 = (const float*)d_in[12];
    const float* Wc2 = (const float*)d_in[13];
    const float* bc2 = (const float*)d_in[14];

    float* ws = (float*)d_ws;
    float* h   = ws;                                          // 131072
    float* u   = ws + 131072;                                 // 131072
    unsigned short* vTh = (unsigned short*)(ws + 262144);     // 131072 bf16
    unsigned short* vTl = (unsigned short*)(ws + 327680);     // 131072 bf16
    float* P   = ws + 393216;                                 // 8 x 131072
    unsigned short* adjH = (unsigned short*)(ws + 1441792);   // 1M bf16
    unsigned short* adjL = (unsigned short*)(ws + 1966080);   // 1M bf16
    float* hi  = ws + 2490368;                                // 131072
    float* hj  = ws + 2621440;                                // 131072
    float* S1  = ws + 2752512;                                // 1024
    float* S2  = ws + 2753536;                                // 1024
    float* lossAcc = ws + 2754560;                            // 1
    unsigned* counter = (unsigned*)(ws + 2754561);            // 1

    k_prep_embuv<<<1280, 256, 0, stream>>>(adj, adjH, adjL, nf, We, be,
                                           Wu, bu, Wv, bv, h, u, vTh, vTl, lossAcc, counter);
    for (int l = 0; l < 3; ++l) {
        k_agg<<<1024, 256, 0, stream>>>(adjH, adjL, vTh, vTl, P);
        if (l < 2)
            k_gateuv<<<256, 256, 0, stream>>>(P, u, h, Wg + l * 32768, bg + l * 128,
                                              Wu + (l + 1) * 16384, bu + (l + 1) * 128,
                                              Wv + (l + 1) * 16384, bv + (l + 1) * 128,
                                              vTh, vTl);
        else
            k_gatecls<<<256, 256, 0, stream>>>(P, u, h, Wg + 2 * 32768, bg + 2 * 128,
                                               Wc1, bc1, Wc2, hi, hj, S1, S2);
    }
    k_edge<<<256, 256, 0, stream>>>(hi, hj, S1, S2, Wc2, bc2, adj, ew,
                                    (float*)d_out, lossAcc, counter);
}